// Round 2
// baseline (455.135 us; speedup 1.0000x reference)
//
#include <hip/hip_runtime.h>
#include <math.h>

// Problem constants
static const int B_  = 4;
static const int CE_ = 128;
static const int CD_ = 256;
static const int HE_ = 256;   // = WE
static const int HD_ = 128;   // = WD
static const int N_  = 16;
#define PLANE  65536          // HE*WE = 256*256
#define DPLANE 16384          // HD*WD = 128*128
#define UPSCALE (127.0f/255.0f)

// ---------------------------------------------------------------------------
// Phase A: horizontally fused stats kernel.
//   blocks [0,1024)    : enc per-pixel stats (max/mean/proj over channels)
//   blocks [1024,1536) : enc per-channel stats (mean/max over pixels)
//   blocks [1536,2560) : dec per-pixel stats (bilinear up2 + relu on the fly)
//   blocks [2560,3584) : dec per-channel stats over virtual upsampled plane
// 256 threads per block.
// ---------------------------------------------------------------------------
__global__ __launch_bounds__(256) void k_stats(
    const float* __restrict__ xe, const float* __restrict__ xd,
    const float* __restrict__ sw1e, const float* __restrict__ sb1e,
    const float* __restrict__ sw1d, const float* __restrict__ sb1d,
    float* __restrict__ stats, float* __restrict__ eav, float* __restrict__ emx,
    float* __restrict__ dav, float* __restrict__ dmx) {
  __shared__ float smem[512];
  int blk = blockIdx.x;
  int t = threadIdx.x;

  if (blk < 1024) {
    // ---- enc per-pixel: one block per (b,row), thread = col --------------
    int b = blk >> 8, h = blk & 255;
    float bias = sb1e[0];
    if (t < CE_) smem[t] = sw1e[t];
    __syncthreads();
    const float* base = xe + (((size_t)b * CE_) * HE_ + h) * (size_t)HE_ + t;
    float mx = -INFINITY, sm = 0.f, pj = 0.f;
#pragma unroll 4
    for (int c = 0; c < CE_; ++c) {
      float v = base[(size_t)c * PLANE];
      mx = fmaxf(mx, v);
      sm += v;
      pj = fmaf(v, smem[c], pj);
    }
    size_t o = (((size_t)b * 6) * HE_ + h) * (size_t)HE_ + t;
    stats[o] = mx;
    stats[o + (size_t)PLANE] = sm * (1.f / CE_);
    stats[o + 2 * (size_t)PLANE] = pj + bias;

  } else if (blk < 1536) {
    // ---- enc per-channel: one block per (b,c) ----------------------------
    int bc = blk - 1024;
    const float4* p = (const float4*)(xe + (size_t)bc * PLANE);
    float sm = 0.f, m = -INFINITY;
    for (int i = t; i < PLANE / 4; i += 256) {
      float4 v = p[i];
      sm += (v.x + v.y) + (v.z + v.w);
      m = fmaxf(m, fmaxf(fmaxf(v.x, v.y), fmaxf(v.z, v.w)));
    }
    float* ss = smem;
    float* sx = smem + 256;
    ss[t] = sm; sx[t] = m;
    __syncthreads();
    for (int s = 128; s > 0; s >>= 1) {
      if (t < s) { ss[t] += ss[t + s]; sx[t] = fmaxf(sx[t], sx[t + s]); }
      __syncthreads();
    }
    if (t == 0) { eav[bc] = ss[0] * (1.f / PLANE); emx[bc] = sx[0]; }

  } else if (blk < 2560) {
    // ---- dec per-pixel (up2 align_corners + relu fused) ------------------
    int bh = blk - 1536;
    int b = bh >> 8, h = bh & 255;
    float bias = sb1d[0];
    smem[t] = sw1d[t];   // CD_ = 256 weights
    __syncthreads();
    float ph = (float)h * UPSCALE;
    int ih0 = (int)ph; float wh = ph - (float)ih0;
    int ih1 = min(ih0 + 1, HD_ - 1);
    float pw = (float)t * UPSCALE;
    int iw0 = (int)pw; float ww = pw - (float)iw0;
    int iw1 = min(iw0 + 1, HD_ - 1);
    float w00 = (1.f - wh) * (1.f - ww), w01 = (1.f - wh) * ww;
    float w10 = wh * (1.f - ww),        w11 = wh * ww;
    const float* xb = xd + (size_t)b * CD_ * DPLANE;
    int o00 = ih0 * HD_ + iw0, o01 = ih0 * HD_ + iw1;
    int o10 = ih1 * HD_ + iw0, o11 = ih1 * HD_ + iw1;
    float mx = -INFINITY, sm = 0.f, pj = 0.f;
#pragma unroll 2
    for (int c = 0; c < CD_; ++c) {
      const float* pc = xb + (size_t)c * DPLANE;
      float v = w00 * pc[o00] + w01 * pc[o01] + w10 * pc[o10] + w11 * pc[o11];
      v = fmaxf(v, 0.f);
      mx = fmaxf(mx, v);
      sm += v;
      pj = fmaf(v, smem[c], pj);
    }
    size_t o = (((size_t)b * 6 + 3) * HE_ + h) * (size_t)HE_ + t;
    stats[o] = mx;
    stats[o + (size_t)PLANE] = sm * (1.f / CD_);
    stats[o + 2 * (size_t)PLANE] = pj + bias;

  } else {
    // ---- dec per-channel over virtual upsampled+relu plane ---------------
    int bc = blk - 2560;
    const float* p = xd + (size_t)bc * DPLANE;
    float pw = (float)t * UPSCALE;
    int iw0 = (int)pw; float ww = pw - (float)iw0;
    int iw1 = min(iw0 + 1, HD_ - 1);
    float sm = 0.f, m = -INFINITY;
#pragma unroll 4
    for (int hh = 0; hh < 256; ++hh) {
      float ph = (float)hh * UPSCALE;
      int ih0 = (int)ph; float wh = ph - (float)ih0;
      int ih1 = min(ih0 + 1, HD_ - 1);
      const float* r0 = p + ih0 * HD_;
      const float* r1 = p + ih1 * HD_;
      float top = r0[iw0] * (1.f - ww) + r0[iw1] * ww;
      float bot = r1[iw0] * (1.f - ww) + r1[iw1] * ww;
      float v = fmaxf((1.f - wh) * top + wh * bot, 0.f);
      sm += v;
      m = fmaxf(m, v);
    }
    float* ss = smem;
    float* sx = smem + 256;
    ss[t] = sm; sx[t] = m;
    __syncthreads();
    for (int s = 128; s > 0; s >>= 1) {
      if (t < s) { ss[t] += ss[t + s]; sx[t] = fmaxf(sx[t], sx[t + s]); }
      __syncthreads();
    }
    if (t == 0) { dav[bc] = ss[0] * (1.f / PLANE); dmx[bc] = sx[0]; }
  }
}

// ---------------------------------------------------------------------------
// Phase B: fused SAG conv + CAG MLP + final gate.
// grid = B*256 blocks (b,row), 256 threads (col).
// Each block:
//   1. computes CAG ch[b,0..127] redundantly (cheap; weights L2-resident)
//   2. computes spat row via dual 7x7x3 conv on stats
//   3. gates all 128 enc channels of its row with float4 IO
// ---------------------------------------------------------------------------
__global__ __launch_bounds__(256) void k_gate(
    const float* __restrict__ stats,
    const float* __restrict__ we, const float* __restrict__ be,
    const float* __restrict__ wd, const float* __restrict__ bd,
    const float* __restrict__ eav, const float* __restrict__ emx,
    const float* __restrict__ dav, const float* __restrict__ dmx,
    const float* __restrict__ cw_ea, const float* __restrict__ cb_ea,
    const float* __restrict__ cw_em, const float* __restrict__ cb_em,
    const float* __restrict__ cw_da, const float* __restrict__ cb_da,
    const float* __restrict__ cw_dm, const float* __restrict__ cb_dm,
    const float* __restrict__ cw_f, const float* __restrict__ cb_f,
    const float* __restrict__ x, float* __restrict__ out) {
  int bh = blockIdx.x;
  int b = bh >> 8, h = bh & 255;
  int t = threadIdx.x;
  int w = t;

  __shared__ float swE[147], swD[147];
  __shared__ float part[16][17];   // [n][slice], padded
  __shared__ float s_n[16];
  __shared__ float s_ch[128];
  __shared__ float s_spat[256];

  if (t < 147) { swE[t] = we[t]; swD[t] = wd[t]; }

  // ---- CAG partial dot products: thread t -> (n = t&15, slice = t>>4) ----
  {
    int n = t & 15, sl = t >> 4;
    const float* ea = eav + b * CE_;
    const float* em = emx + b * CE_;
    const float* da = dav + b * CD_;
    const float* dm = dmx + b * CD_;
    float p = 0.f;
#pragma unroll
    for (int i = 0; i < 8; ++i) {
      int c = sl * 8 + i;
      p = fmaf(ea[c], cw_ea[n * CE_ + c], p);
      p = fmaf(em[c], cw_em[n * CE_ + c], p);
    }
#pragma unroll
    for (int i = 0; i < 16; ++i) {
      int c = sl * 16 + i;
      p = fmaf(da[c], cw_da[n * CD_ + c], p);
      p = fmaf(dm[c], cw_dm[n * CD_ + c], p);
    }
    part[n][sl] = p;
  }
  __syncthreads();
  if (t < 16) {
    float s = cb_ea[t] + cb_em[t] + cb_da[t] + cb_dm[t];
#pragma unroll
    for (int sl = 0; sl < 16; ++sl) s += part[t][sl];
    s_n[t] = s;
  }
  __syncthreads();
  if (t < 128) {
    float s = cb_f[t];
#pragma unroll
    for (int n = 0; n < N_; ++n) s = fmaf(s_n[n], cw_f[t * N_ + n], s);
    s_ch[t] = 1.f / (1.f + __expf(-s));
  }

  // ---- SAG dual conv 7x7 over 3 stat channels each -----------------------
  float acc = be[0] + bd[0];
  const float* sb = stats + ((size_t)b * 6) * PLANE;
#pragma unroll
  for (int ic = 0; ic < 3; ++ic) {
    const float* pe = sb + (size_t)ic * PLANE;
    const float* pd = sb + (size_t)(ic + 3) * PLANE;
#pragma unroll
    for (int ky = 0; ky < 7; ++ky) {
      int y = h + ky - 3;
      if ((unsigned)y >= 256u) continue;
      const float* rowE = pe + y * 256;
      const float* rowD = pd + y * 256;
#pragma unroll
      for (int kx = 0; kx < 7; ++kx) {
        int xw = w + kx - 3;
        if ((unsigned)xw >= 256u) continue;
        float we_ = swE[ic * 49 + ky * 7 + kx];
        float wd_ = swD[ic * 49 + ky * 7 + kx];
        acc = fmaf(rowE[xw], we_, acc);
        acc = fmaf(rowD[xw], wd_, acc);
      }
    }
  }
  s_spat[w] = 1.f / (1.f + __expf(-acc));
  __syncthreads();

  // ---- final gate: out = x * spat * ch, float4 IO ------------------------
  int w4 = t & 63;     // float4 index within the 256-wide row
  int cq = t >> 6;     // channel phase 0..3 (wave-uniform)
  float4 sv = ((const float4*)s_spat)[w4];
  const float4* xp = (const float4*)x + ((size_t)b * CE_) * (PLANE / 4) + h * 64;
  float4*       op = (float4*)out     + ((size_t)b * CE_) * (PLANE / 4) + h * 64;
  for (int c = cq; c < CE_; c += 4) {
    float cv = s_ch[c];
    float4 xv = xp[(size_t)c * (PLANE / 4) + w4];
    float4 o;
    o.x = xv.x * sv.x * cv;
    o.y = xv.y * sv.y * cv;
    o.z = xv.z * sv.z * cv;
    o.w = xv.w * sv.w * cv;
    op[(size_t)c * (PLANE / 4) + w4] = o;
  }
}

// ---------------------------------------------------------------------------
extern "C" void kernel_launch(void* const* d_in, const int* in_sizes, int n_in,
                              void* d_out, int out_size, void* d_ws, size_t ws_size,
                              hipStream_t stream) {
  const float* x_enc = (const float*)d_in[0];
  const float* x_dec = (const float*)d_in[1];
  const float* cw_ea = (const float*)d_in[2];
  const float* cb_ea = (const float*)d_in[3];
  const float* cw_em = (const float*)d_in[4];
  const float* cb_em = (const float*)d_in[5];
  const float* cw_da = (const float*)d_in[6];
  const float* cb_da = (const float*)d_in[7];
  const float* cw_dm = (const float*)d_in[8];
  const float* cb_dm = (const float*)d_in[9];
  const float* cw_f  = (const float*)d_in[10];
  const float* cb_f  = (const float*)d_in[11];
  const float* sw1_e = (const float*)d_in[12];
  const float* sb1_e = (const float*)d_in[13];
  const float* sw2_e = (const float*)d_in[14];
  const float* sb2_e = (const float*)d_in[15];
  const float* sw1_d = (const float*)d_in[16];
  const float* sb1_d = (const float*)d_in[17];
  const float* sw2_d = (const float*)d_in[18];
  const float* sb2_d = (const float*)d_in[19];
  float* out = (float*)d_out;
  (void)in_sizes; (void)n_in; (void)out_size; (void)ws_size;

  // workspace layout (floats)
  float* ws    = (float*)d_ws;
  float* stats = ws;                       // B*6*PLANE = 1,572,864
  float* eav   = ws + 1572864;             // B*CE = 512
  float* emx   = eav + 512;                // 512
  float* dav   = emx + 512;                // B*CD = 1024
  float* dmx   = dav + 1024;               // 1024

  k_stats<<<3584, 256, 0, stream>>>(x_enc, x_dec, sw1_e, sb1_e, sw1_d, sb1_d,
                                    stats, eav, emx, dav, dmx);
  k_gate <<<B_ * HE_, 256, 0, stream>>>(stats, sw2_e, sb2_e, sw2_d, sb2_d,
                                        eav, emx, dav, dmx,
                                        cw_ea, cb_ea, cw_em, cb_em,
                                        cw_da, cb_da, cw_dm, cb_dm,
                                        cw_f, cb_f, x_enc, out);
}